// Round 1
// 339.143 us; speedup vs baseline: 1.0348x; 1.0348x over previous
//
#include <hip/hip_runtime.h>
#include <math.h>

// Problem constants
#define BB 8
#define SS 8192
#define DD 512
#define HH 256
#define MM (BB * SS)        // 65536 rows
#define NN 768              // 3H columns
// Scan chunking
#define CC 64
#define LL 128

typedef unsigned short u16;
typedef __attribute__((ext_vector_type(8))) short short8;   // 8 bf16 = MFMA A/B frag
typedef __attribute__((ext_vector_type(4))) float f32x4;    // MFMA C/D frag

#define AS1(p) ((const __attribute__((address_space(1))) void*)(p))
#define AS3(p) ((__attribute__((address_space(3))) void*)(p))

__device__ __forceinline__ u16 f2bf_rtne(float f) {
    union { float f; unsigned u; } v; v.f = f;
    unsigned r = v.u + 0x7fffu + ((v.u >> 16) & 1u);
    return (u16)(r >> 16);
}
// pack two floats -> two bf16 (round-to-nearest, no tie-even): low16 = a, high16 = b
__device__ __forceinline__ unsigned pack2_rtn(float a, float b) {
    union { float f; unsigned u; } x, y; x.f = a; y.f = b;
    return ((x.u + 0x8000u) >> 16) | ((y.u + 0x8000u) & 0xffff0000u);
}

__device__ __forceinline__ float sp_fast(float z) {    // softplus
    return (z > 15.0f) ? z : __logf(1.0f + __expf(z));
}

// ---- W fp32 [3H,D] -> Wr bf16, permuted into DMA staging order WITH the LDS
// XOR-swizzle baked in (DMA dest must stay linear; source is pre-swizzled).
// Read side expects logical element (row r, quad q) of a 24KB chunk at 16B-unit
//   u = (4r + q) ^ (r & 7)
// Inverse (what logical element lands at flat unit u):
//   r = ((u>>2) & ~1) | ((u>>2 ^ u>>4) & 1);  q = (u&3) ^ (r&3)
// Then (unchanged): col c = half*384 + r; hg=c/48; g=(c%48)/16; hl=c%16
//   W row = g*256 + hg*16 + hl;  k = kc*32 + q*8
__global__ __launch_bounds__(256) void convert_W(const float* __restrict__ W,
                                                 u16* __restrict__ Wr) {
    const int chunk = blockIdx.x * 256 + threadIdx.x;    // 0..49151 (16B units)
    const int kh = chunk / 1536;
    const int u = chunk % 1536;
    const int cl = ((u >> 2) & ~1) | (((u >> 2) ^ (u >> 4)) & 1);
    const int qq = (u & 3) ^ (cl & 3);
    const int kc = kh >> 1, half = kh & 1;
    const int c = half * 384 + cl;
    const int hg = c / 48, r48 = c % 48;
    const int g = r48 >> 4, hl = r48 & 15;
    const int wrow = g * HH + hg * 16 + hl;
    const int k0 = kc * 32 + qq * 8;
    const float4 v0 = *(const float4*)&W[(size_t)wrow * DD + k0];
    const float4 v1 = *(const float4*)&W[(size_t)wrow * DD + k0 + 4];
    u16 o[8];
    o[0]=f2bf_rtne(v0.x); o[1]=f2bf_rtne(v0.y); o[2]=f2bf_rtne(v0.z); o[3]=f2bf_rtne(v0.w);
    o[4]=f2bf_rtne(v1.x); o[5]=f2bf_rtne(v1.y); o[6]=f2bf_rtne(v1.z); o[7]=f2bf_rtne(v1.w);
    *(uint4*)&Wr[(size_t)chunk * 8] = *(const uint4*)o;
}

// ---- Fused MFMA GEMM + gates, v4.
// 3-buffer counted-vmcnt pipeline: one raw s_barrier per 24KB B-chunk, DMA for
// chunk s+2 stays in flight across two compute phases; never vmcnt(0) in loop.
// B ds_reads XOR-swizzled (convert_W pre-swizzles the source) -> 2-way banks.
__global__ __launch_bounds__(512) void gemm_gate_mfma(
    const float* __restrict__ x,      // [M,512] fp32
    const u16* __restrict__ Wr,       // permuted+swizzled bf16
    float* __restrict__ F_arr,        // [M,H]
    float* __restrict__ u_out)        // d_out: [M,H]
{
    __shared__ __align__(16) u16 Bs[3][12288];        // 3 x 24 KB chunks
    __shared__ __align__(16) u16 As[2][64 * 40];      // 2 x 5 KB, row stride 40 shorts

    const int tid = threadIdx.x;
    const int m0 = blockIdx.x * 64;
    const int w = tid >> 6;          // wave 0..7
    const int lane = tid & 63;
    const int l16 = lane & 15;
    const int quad = lane >> 4;      // 0..3

    const int arow = tid >> 3;       // 0..63
    const int aqi = tid & 7;         // 0..7

    f32x4 acc[4][6];
    #pragma unroll
    for (int a = 0; a < 4; ++a)
        #pragma unroll
        for (int b = 0; b < 6; ++b)
            #pragma unroll
            for (int e = 0; e < 4; ++e) acc[a][b][e] = 0.0f;

    // swizzled B read offsets (in shorts), one per jn
    int boff[3];
    #pragma unroll
    for (int jn = 0; jn < 3; ++jn) {
        const int r = (w * 3 + jn) * 16 + l16;
        boff[jn] = ((r * 4 + quad) ^ (r & 7)) * 8;
    }

    const float* xrow = &x[(size_t)(m0 + arow) * DD];

    // ---- prologue ----
    // per-wave vmem queue after prologue: [v0, aL(x1), B0(3), B1(3)]
    const float4 v0 = *(const float4*)&xrow[aqi * 4];
    float4 a_reg = *(const float4*)&xrow[32 + aqi * 4];
    asm volatile("" ::: "memory");
    #pragma unroll
    for (int i = 0; i < 3; ++i) {
        const int idx = i * 512 + tid;
        __builtin_amdgcn_global_load_lds(AS1(Wr + (size_t)idx * 8),
                                         AS3(&Bs[0][idx * 8]), 16, 0, 0);
    }
    #pragma unroll
    for (int i = 0; i < 3; ++i) {
        const int idx = i * 512 + tid;
        __builtin_amdgcn_global_load_lds(AS1(Wr + 12288 + (size_t)idx * 8),
                                         AS3(&Bs[1][idx * 8]), 16, 0, 0);
    }
    *(uint2*)&As[0][arow * 40 + aqi * 4] =
        make_uint2(pack2_rtn(v0.x, v0.y), pack2_rtn(v0.z, v0.w));

    int cur = 0;          // buffer holding chunk 2kc
    short8 afr[4];
    for (int kc = 0; kc < 15; ++kc) {
        const int nb1 = (cur + 2 > 2) ? cur - 1 : cur + 2;   // (cur+2)%3
        const int c1  = (cur + 1 > 2) ? 0 : cur + 1;         // (cur+1)%3

        // ---- half 0 (chunk 2kc) ----
        // in flight: aL(x_{kc+1}), B(2kc)(3), B(2kc+1)(3) -> wait 3 retires aL+B(2kc)
        asm volatile("s_waitcnt lgkmcnt(0)" ::: "memory");
        asm volatile("s_waitcnt vmcnt(3)" ::: "memory");
        __builtin_amdgcn_s_barrier();
        __builtin_amdgcn_sched_barrier(0);
        #pragma unroll
        for (int mf = 0; mf < 4; ++mf)
            afr[mf] = *(const short8*)&As[kc & 1][(mf * 16 + l16) * 40 + quad * 8];
        short8 bfr[3];
        #pragma unroll
        for (int jn = 0; jn < 3; ++jn)
            bfr[jn] = *(const short8*)&Bs[cur][boff[jn]];
        // stage A(kc+1) from regs; prefetch x(kc+2)
        *(uint2*)&As[(kc + 1) & 1][arow * 40 + aqi * 4] =
            make_uint2(pack2_rtn(a_reg.x, a_reg.y), pack2_rtn(a_reg.z, a_reg.w));
        {
            const int knext = (kc + 2 < 16) ? (kc + 2) : 15;
            a_reg = *(const float4*)&xrow[knext * 32 + aqi * 4];
        }
        // issue B(2kc+2) -> Bs[nb1]  (its previous chunk's readers drained above)
        {
            const size_t gbase = (size_t)(2 * kc + 2) * 12288;
            #pragma unroll
            for (int i = 0; i < 3; ++i) {
                const int idx = i * 512 + tid;
                __builtin_amdgcn_global_load_lds(AS1(Wr + gbase + (size_t)idx * 8),
                                                 AS3(&Bs[nb1][idx * 8]), 16, 0, 0);
            }
        }
        __builtin_amdgcn_sched_barrier(0);
        __builtin_amdgcn_s_setprio(1);
        #pragma unroll
        for (int mf = 0; mf < 4; ++mf)
            #pragma unroll
            for (int jn = 0; jn < 3; ++jn)
                acc[mf][jn] = __builtin_amdgcn_mfma_f32_16x16x32_bf16(
                    afr[mf], bfr[jn], acc[mf][jn], 0, 0, 0);
        __builtin_amdgcn_s_setprio(0);

        // ---- half 1 (chunk 2kc+1) ----
        // in flight: B(2kc+1)(3 oldest), {aL, B(2kc+2)(3)} -> wait 4 retires B(2kc+1)
        asm volatile("s_waitcnt lgkmcnt(0)" ::: "memory");
        asm volatile("s_waitcnt vmcnt(4)" ::: "memory");
        __builtin_amdgcn_s_barrier();
        __builtin_amdgcn_sched_barrier(0);
        #pragma unroll
        for (int jn = 0; jn < 3; ++jn)
            bfr[jn] = *(const short8*)&Bs[c1][boff[jn]];
        // issue B(2kc+3) -> Bs[cur]  (chunk 2kc readers drained above)
        {
            const size_t gbase = (size_t)(2 * kc + 3) * 12288;
            #pragma unroll
            for (int i = 0; i < 3; ++i) {
                const int idx = i * 512 + tid;
                __builtin_amdgcn_global_load_lds(AS1(Wr + gbase + (size_t)idx * 8),
                                                 AS3(&Bs[cur][idx * 8]), 16, 0, 0);
            }
        }
        __builtin_amdgcn_sched_barrier(0);
        __builtin_amdgcn_s_setprio(1);
        #pragma unroll
        for (int mf = 0; mf < 4; ++mf)
            #pragma unroll
            for (int jn = 0; jn < 3; ++jn)
                acc[mf][3 + jn] = __builtin_amdgcn_mfma_f32_16x16x32_bf16(
                    afr[mf], bfr[jn], acc[mf][3 + jn], 0, 0, 0);
        __builtin_amdgcn_s_setprio(0);

        cur = nb1;
    }
    // keep final (clamped) prefetch alive so vmcnt bookkeeping stays exact
    asm volatile("" :: "v"(a_reg.x), "v"(a_reg.y), "v"(a_reg.z), "v"(a_reg.w));

    // ---- tail kc=15: chunk 30 in Bs[cur], chunk 31 in Bs[(cur+1)%3] ----
    asm volatile("s_waitcnt lgkmcnt(0)" ::: "memory");
    asm volatile("s_waitcnt vmcnt(3)" ::: "memory");   // retires {aL, B30}
    __builtin_amdgcn_s_barrier();
    __builtin_amdgcn_sched_barrier(0);
    #pragma unroll
    for (int mf = 0; mf < 4; ++mf)
        afr[mf] = *(const short8*)&As[1][(mf * 16 + l16) * 40 + quad * 8];
    {
        short8 bfr[3];
        #pragma unroll
        for (int jn = 0; jn < 3; ++jn)
            bfr[jn] = *(const short8*)&Bs[cur][boff[jn]];
        __builtin_amdgcn_s_setprio(1);
        #pragma unroll
        for (int mf = 0; mf < 4; ++mf)
            #pragma unroll
            for (int jn = 0; jn < 3; ++jn)
                acc[mf][jn] = __builtin_amdgcn_mfma_f32_16x16x32_bf16(
                    afr[mf], bfr[jn], acc[mf][jn], 0, 0, 0);
        __builtin_amdgcn_s_setprio(0);
    }
    asm volatile("s_waitcnt lgkmcnt(0)" ::: "memory");
    asm volatile("s_waitcnt vmcnt(0)" ::: "memory");   // retires B31 (last 3)
    __builtin_amdgcn_s_barrier();
    __builtin_amdgcn_sched_barrier(0);
    {
        const int c1 = (cur + 1 > 2) ? 0 : cur + 1;
        short8 bfr[3];
        #pragma unroll
        for (int jn = 0; jn < 3; ++jn)
            bfr[jn] = *(const short8*)&Bs[c1][boff[jn]];
        __builtin_amdgcn_s_setprio(1);
        #pragma unroll
        for (int mf = 0; mf < 4; ++mf)
            #pragma unroll
            for (int jn = 0; jn < 3; ++jn)
                acc[mf][3 + jn] = __builtin_amdgcn_mfma_f32_16x16x32_bf16(
                    afr[mf], bfr[jn], acc[mf][3 + jn], 0, 0, 0);
        __builtin_amdgcn_s_setprio(0);
    }

    // ---- epilogue: gates. head = (half*8 + w)*16 + l16, gate g = jn ----
    #pragma unroll
    for (int half = 0; half < 2; ++half) {
        const int head = (half * 8 + w) * 16 + l16;
        #pragma unroll
        for (int mf = 0; mf < 4; ++mf) {
            #pragma unroll
            for (int r = 0; r < 4; ++r) {
                const int m = m0 + mf * 16 + quad * 4 + r;
                const float fr = acc[mf][half * 3 + 0][r];
                const float ir = acc[mf][half * 3 + 1][r];
                const float hr = acc[mf][half * 3 + 2][r];
                const float diff = sp_fast(-fr) - sp_fast(-ir);
                const float F = __builtin_amdgcn_rcpf(1.0f + __expf(diff));
                const float I = 1.0f - F;
                const float G = (hr >= 0.0f) ? (hr + 0.5f)
                                             : __builtin_amdgcn_rcpf(1.0f + __expf(-hr));
                const size_t o = (size_t)m * HH + head;
                F_arr[o] = F;
                u_out[o] = I * G;
            }
        }
    }
}

// ---- Scan passes: float2 over h (8 B/lane), deeper unroll ----
__global__ __launch_bounds__(256) void scan_pass1(
    const float* __restrict__ F_arr, const float* __restrict__ u_arr,
    float* __restrict__ P_arr, float* __restrict__ U_arr) {
    const int pair = blockIdx.x * 2 + (threadIdx.x >> 7);   // (b,c) index 0..511
    const int b = pair / CC;
    const int c = pair % CC;
    const int h0 = (threadIdx.x & 127) * 2;
    size_t base = ((size_t)(b * SS + c * LL)) * HH + h0;
    float P0 = 1.0f, P1 = 1.0f, U0 = 0.0f, U1 = 0.0f;
    #pragma unroll 8
    for (int t = 0; t < LL; ++t) {
        const float2 F = *(const float2*)&F_arr[base];
        const float2 u = *(const float2*)&u_arr[base];
        U0 = F.x * U0 + u.x;
        U1 = F.y * U1 + u.y;
        P0 *= F.x;
        P1 *= F.y;
        base += HH;
    }
    const size_t o = ((size_t)c * BB + b) * HH + h0;
    *(float2*)&P_arr[o] = make_float2(P0, P1);
    *(float2*)&U_arr[o] = make_float2(U0, U1);
}

__global__ __launch_bounds__(256) void scan_pass2(
    const float* __restrict__ h_prev, const float* __restrict__ P_arr,
    const float* __restrict__ U_arr, float* __restrict__ Hin) {
    const int b = blockIdx.x;
    const int h = threadIdx.x;
    const float z = h_prev[b * HH + h];
    float carry = (z >= 0.0f) ? (z + 0.5f) : __builtin_amdgcn_rcpf(1.0f + __expf(-z));
    #pragma unroll 4
    for (int c = 0; c < CC; ++c) {
        const size_t o = ((size_t)c * BB + b) * HH + h;
        Hin[o] = carry;
        carry = P_arr[o] * carry + U_arr[o];
    }
}

__global__ __launch_bounds__(256) void scan_pass3(
    const float* __restrict__ F_arr, const float* __restrict__ Hin,
    float* __restrict__ out) {
    const int pair = blockIdx.x * 2 + (threadIdx.x >> 7);
    const int b = pair / CC;
    const int c = pair % CC;
    const int h0 = (threadIdx.x & 127) * 2;
    float2 hv = *(const float2*)&Hin[((size_t)c * BB + b) * HH + h0];
    size_t base = ((size_t)(b * SS + c * LL)) * HH + h0;
    #pragma unroll 8
    for (int t = 0; t < LL; ++t) {
        const float2 F = *(const float2*)&F_arr[base];
        const float2 u = *(const float2*)&out[base];
        hv.x = F.x * hv.x + u.x;
        hv.y = F.y * hv.y + u.y;
        *(float2*)&out[base] = hv;
        base += HH;
    }
}

extern "C" void kernel_launch(void* const* d_in, const int* in_sizes, int n_in,
                              void* d_out, int out_size, void* d_ws, size_t ws_size,
                              hipStream_t stream) {
    const float* x      = (const float*)d_in[0];   // [B,S,D]
    const float* h_prev = (const float*)d_in[1];   // [B,H]
    const float* W      = (const float*)d_in[2];   // [3H,D]

    // Workspace: F_arr [M*H] f32 | P | U | Hin | Wr [768*512] bf16  (~69.4 MB, proven)
    float* F_arr = (float*)d_ws;
    float* P_arr = F_arr + (size_t)MM * HH;
    float* U_arr = P_arr + (size_t)CC * BB * HH;
    float* Hin   = U_arr + (size_t)CC * BB * HH;
    u16*   Wr    = (u16*)(Hin + (size_t)CC * BB * HH);

    convert_W<<<192, 256, 0, stream>>>(W, Wr);
    gemm_gate_mfma<<<MM / 64, 512, 0, stream>>>(x, Wr, F_arr, (float*)d_out);
    scan_pass1<<<BB * CC / 2, 256, 0, stream>>>(F_arr, (const float*)d_out, P_arr, U_arr);
    scan_pass2<<<BB, HH, 0, stream>>>(h_prev, P_arr, U_arr, Hin);
    scan_pass3<<<BB * CC / 2, 256, 0, stream>>>(F_arr, Hin, (float*)d_out);
}

// Round 3
// 332.964 us; speedup vs baseline: 1.0540x; 1.0186x over previous
//
#include <hip/hip_runtime.h>
#include <hip/hip_fp16.h>
#include <math.h>

// Problem constants
#define BB 8
#define SS 8192
#define DD 512
#define HH 256
#define MM (BB * SS)        // 65536 rows
#define NN 768              // 3H columns
// Scan chunking
#define CC 256
#define LL 32

typedef unsigned short u16;
typedef __attribute__((ext_vector_type(8))) short short8;   // 8 bf16 = MFMA A/B frag
typedef __attribute__((ext_vector_type(4))) float f32x4;    // MFMA C/D frag

#define AS1(p) ((const __attribute__((address_space(1))) void*)(p))
#define AS3(p) ((__attribute__((address_space(3))) void*)(p))

__device__ __forceinline__ u16 f2bf_rtne(float f) {
    union { float f; unsigned u; } v; v.f = f;
    unsigned r = v.u + 0x7fffu + ((v.u >> 16) & 1u);
    return (u16)(r >> 16);
}
// pack two floats -> two bf16 (round-to-nearest): low16 = a, high16 = b
__device__ __forceinline__ unsigned pack2_rtn(float a, float b) {
    union { float f; unsigned u; } x, y; x.f = a; y.f = b;
    return ((x.u + 0x8000u) >> 16) | ((y.u + 0x8000u) & 0xffff0000u);
}

__device__ __forceinline__ float sp_fast(float z) {    // softplus
    return (z > 15.0f) ? z : __logf(1.0f + __expf(z));
}

__device__ __forceinline__ unsigned packFu(float F, float u) {
    __half2 h = __floats2half2_rn(F, u);
    return *reinterpret_cast<unsigned*>(&h);
}
__device__ __forceinline__ float2 unpackFu(unsigned v) {
    __half2 h = *reinterpret_cast<__half2*>(&v);
    return __half22float2(h);
}

// ---- W fp32 [3H,D] -> Wr bf16, permuted into DMA staging order for the
// BN=192 column-block layout, with the LDS XOR-swizzle baked into the source.
// Chunk (kc, cb) = 768 16B-units; logical (r,q) lives at unit u=(4r+q)^(r&7).
// Inverse: v=u&31; s=((v>>2)&7)^((v>>4)&1); q=(v&3)^(s&3); r=(u>>5)*8+s.
// Column map: r = w*48 + jn*16 + hl  ->  W row = jn*256 + cb*64 + w*16 + hl,
// k = kc*32 + q*8.
__global__ __launch_bounds__(256) void convert_W(const float* __restrict__ W,
                                                 u16* __restrict__ Wr) {
    const int chunk = blockIdx.x * 256 + threadIdx.x;    // 0..49151 (16B units)
    const int kcb = chunk / 768;       // kc*4 + cb
    const int u = chunk % 768;
    const int kc = kcb >> 2, cb = kcb & 3;
    const int v = u & 31;
    const int s = ((v >> 2) & 7) ^ ((v >> 4) & 1);
    const int q = (v & 3) ^ (s & 3);
    const int r = ((u >> 5) << 3) | s;        // 0..191
    const int w = r / 48;
    const int rr = r % 48;
    const int jn = rr >> 4, hl = rr & 15;
    const int wrow = jn * HH + cb * 64 + w * 16 + hl;
    const int k0 = kc * 32 + q * 8;
    const float4 v0 = *(const float4*)&W[(size_t)wrow * DD + k0];
    const float4 v1 = *(const float4*)&W[(size_t)wrow * DD + k0 + 4];
    u16 o[8];
    o[0]=f2bf_rtne(v0.x); o[1]=f2bf_rtne(v0.y); o[2]=f2bf_rtne(v0.z); o[3]=f2bf_rtne(v0.w);
    o[4]=f2bf_rtne(v1.x); o[5]=f2bf_rtne(v1.y); o[6]=f2bf_rtne(v1.z); o[7]=f2bf_rtne(v1.w);
    *(uint4*)&Wr[(size_t)chunk * 8] = *(const uint4*)o;
}

// ---- Fused MFMA GEMM + gates, v5: occupancy-first.
// BM=64, BN=192, 256 threads (4 waves), 4 blocks/CU. Grid 4096 with chunked
// XCD swizzle so the 4 column-siblings of each row-block share an XCD's L2.
// Simple 2-buffer LDS + one __syncthreads per kc; inter-block overlap hides
// the drains (m97/m114 mechanism). Output: packed fp16 (F,u) per element.
__global__ __launch_bounds__(256, 4) void gemm_gate_mfma(
    const float* __restrict__ x,      // [M,512] fp32
    const u16* __restrict__ Wr,       // permuted+swizzled bf16
    unsigned* __restrict__ Fu)        // d_out as [M,H] packed half2(F,u)
{
    __shared__ __align__(16) u16 Bs[2][6144];         // 2 x 12 KB (192 cols x 32 k)
    __shared__ __align__(16) u16 As[2][64 * 40];      // 2 x 5 KB, row stride 40 shorts

    const int tid = threadIdx.x;
    // XCD-chunked swizzle (4096 % 8 == 0 -> bijective)
    const int L = (blockIdx.x & 7) * 512 + (blockIdx.x >> 3);
    const int mblk = L >> 2, cb = L & 3;
    const int m0 = mblk * 64;

    const int w = tid >> 6;          // wave 0..3
    const int lane = tid & 63;
    const int l16 = lane & 15;
    const int quad = lane >> 4;      // 0..3

    const int arow = tid >> 2;       // 0..63
    const int aqi = tid & 3;         // 0..3 (8 floats each)

    f32x4 acc[4][3];
    #pragma unroll
    for (int a = 0; a < 4; ++a)
        #pragma unroll
        for (int b = 0; b < 3; ++b)
            #pragma unroll
            for (int e = 0; e < 4; ++e) acc[a][b][e] = 0.0f;

    // swizzled B read offsets (in shorts)
    int boff[3];
    #pragma unroll
    for (int jn = 0; jn < 3; ++jn) {
        const int r = w * 48 + jn * 16 + l16;
        boff[jn] = (((r * 4 + quad) ^ (r & 7))) * 8;
    }

    const float* xrow = &x[(size_t)(m0 + arow) * DD];

    // ---- prologue ----
    {
        const size_t ub = (size_t)(0 * 4 + cb) * 768;
        #pragma unroll
        for (int i = 0; i < 3; ++i) {
            const int idx = i * 256 + tid;
            __builtin_amdgcn_global_load_lds(AS1(Wr + (ub + idx) * 8),
                                             AS3(&Bs[0][idx * 8]), 16, 0, 0);
        }
    }
    float4 va0 = *(const float4*)&xrow[aqi * 8];
    float4 va1 = *(const float4*)&xrow[aqi * 8 + 4];
    float4 ar0 = *(const float4*)&xrow[32 + aqi * 8];
    float4 ar1 = *(const float4*)&xrow[32 + aqi * 8 + 4];
    {
        uint4 p;
        p.x = pack2_rtn(va0.x, va0.y); p.y = pack2_rtn(va0.z, va0.w);
        p.z = pack2_rtn(va1.x, va1.y); p.w = pack2_rtn(va1.z, va1.w);
        *(uint4*)&As[0][arow * 40 + aqi * 8] = p;
    }
    __syncthreads();

    // ---- K loop: 16 kc steps ----
    for (int kc = 0; kc < 16; ++kc) {
        const int buf = kc & 1;
        // issue B(kc+1) DMA into the other buffer (readers drained by last barrier)
        if (kc < 15) {
            const size_t ub = (size_t)((kc + 1) * 4 + cb) * 768;
            #pragma unroll
            for (int i = 0; i < 3; ++i) {
                const int idx = i * 256 + tid;
                __builtin_amdgcn_global_load_lds(AS1(Wr + (ub + idx) * 8),
                                                 AS3(&Bs[buf ^ 1][idx * 8]), 16, 0, 0);
            }
            // stage A(kc+1) from regs
            uint4 p;
            p.x = pack2_rtn(ar0.x, ar0.y); p.y = pack2_rtn(ar0.z, ar0.w);
            p.z = pack2_rtn(ar1.x, ar1.y); p.w = pack2_rtn(ar1.z, ar1.w);
            *(uint4*)&As[buf ^ 1][arow * 40 + aqi * 8] = p;
            if (kc < 14) {   // prefetch x(kc+2)
                ar0 = *(const float4*)&xrow[(kc + 2) * 32 + aqi * 8];
                ar1 = *(const float4*)&xrow[(kc + 2) * 32 + aqi * 8 + 4];
            }
        }
        // fragments for this kc
        short8 afr[4];
        #pragma unroll
        for (int mf = 0; mf < 4; ++mf)
            afr[mf] = *(const short8*)&As[buf][(mf * 16 + l16) * 40 + quad * 8];
        short8 bfr[3];
        #pragma unroll
        for (int jn = 0; jn < 3; ++jn)
            bfr[jn] = *(const short8*)&Bs[buf][boff[jn]];

        __builtin_amdgcn_s_setprio(1);
        #pragma unroll
        for (int mf = 0; mf < 4; ++mf)
            #pragma unroll
            for (int jn = 0; jn < 3; ++jn)
                acc[mf][jn] = __builtin_amdgcn_mfma_f32_16x16x32_bf16(
                    afr[mf], bfr[jn], acc[mf][jn], 0, 0, 0);
        __builtin_amdgcn_s_setprio(0);
        __syncthreads();
    }

    // ---- epilogue: gates -> packed fp16 (F, u) ----
    const int head = cb * 64 + w * 16 + l16;
    #pragma unroll
    for (int mf = 0; mf < 4; ++mf) {
        #pragma unroll
        for (int r = 0; r < 4; ++r) {
            const int m = m0 + mf * 16 + quad * 4 + r;
            const float fr = acc[mf][0][r];
            const float ir = acc[mf][1][r];
            const float hr = acc[mf][2][r];
            const float diff = sp_fast(-fr) - sp_fast(-ir);
            const float F = __builtin_amdgcn_rcpf(1.0f + __expf(diff));
            const float I = 1.0f - F;
            const float G = (hr >= 0.0f) ? (hr + 0.5f)
                                         : __builtin_amdgcn_rcpf(1.0f + __expf(-hr));
            Fu[(size_t)m * HH + head] = packFu(F, I * G);
        }
    }
}

// ---- Scan passes over packed fp16 (F,u), CC=256 chunks of LL=32 ----
__global__ __launch_bounds__(256) void scan_pass1(
    const unsigned* __restrict__ Fu,
    float* __restrict__ P_arr, float* __restrict__ U_arr) {
    const int pair = blockIdx.x * 2 + (threadIdx.x >> 7);   // (b,c) 0..2047
    const int b = pair / CC;
    const int c = pair % CC;
    const int h0 = (threadIdx.x & 127) * 2;
    size_t base = ((size_t)(b * SS + c * LL)) * HH + h0;
    float P0 = 1.0f, P1 = 1.0f, U0 = 0.0f, U1 = 0.0f;
    #pragma unroll 8
    for (int t = 0; t < LL; ++t) {
        const uint2 fu = *(const uint2*)&Fu[base];
        const float2 a = unpackFu(fu.x);
        const float2 d = unpackFu(fu.y);
        U0 = a.x * U0 + a.y;  P0 *= a.x;
        U1 = d.x * U1 + d.y;  P1 *= d.x;
        base += HH;
    }
    const size_t o = ((size_t)c * BB + b) * HH + h0;
    *(float2*)&P_arr[o] = make_float2(P0, P1);
    *(float2*)&U_arr[o] = make_float2(U0, U1);
}

__global__ __launch_bounds__(256) void scan_pass2(
    const float* __restrict__ h_prev, const float* __restrict__ P_arr,
    const float* __restrict__ U_arr, float* __restrict__ Hin) {
    const int b = blockIdx.x;
    const int h = threadIdx.x;
    const float z = h_prev[b * HH + h];
    float carry = (z >= 0.0f) ? (z + 0.5f) : __builtin_amdgcn_rcpf(1.0f + __expf(-z));
    #pragma unroll 8
    for (int c = 0; c < CC; ++c) {
        const size_t o = ((size_t)c * BB + b) * HH + h;
        Hin[o] = carry;
        carry = P_arr[o] * carry + U_arr[o];
    }
}

// In-place: reads packed (F,u) from buf, writes fp32 h over the same words.
__global__ __launch_bounds__(256) void scan_pass3(
    const float* __restrict__ Hin, unsigned* buf) {
    const int pair = blockIdx.x * 2 + (threadIdx.x >> 7);
    const int b = pair / CC;
    const int c = pair % CC;
    const int h0 = (threadIdx.x & 127) * 2;
    float2 hv = *(const float2*)&Hin[((size_t)c * BB + b) * HH + h0];
    size_t base = ((size_t)(b * SS + c * LL)) * HH + h0;
    #pragma unroll 8
    for (int t = 0; t < LL; ++t) {
        const uint2 fu = *(const uint2*)&buf[base];
        const float2 a = unpackFu(fu.x);
        const float2 d = unpackFu(fu.y);
        hv.x = a.x * hv.x + a.y;
        hv.y = d.x * hv.y + d.y;
        *(float2*)&buf[base] = hv;   // same 8 bytes, now fp32 h
        base += HH;
    }
}

extern "C" void kernel_launch(void* const* d_in, const int* in_sizes, int n_in,
                              void* d_out, int out_size, void* d_ws, size_t ws_size,
                              hipStream_t stream) {
    const float* x      = (const float*)d_in[0];   // [B,S,D]
    const float* h_prev = (const float*)d_in[1];   // [B,H]
    const float* W      = (const float*)d_in[2];   // [3H,D]

    // Workspace: P | U | Hin  (each CC*BB*HH f32 = 2 MB) | Wr bf16 (768 KB)
    float* P_arr = (float*)d_ws;
    float* U_arr = P_arr + (size_t)CC * BB * HH;
    float* Hin   = U_arr + (size_t)CC * BB * HH;
    u16*   Wr    = (u16*)(Hin + (size_t)CC * BB * HH);

    convert_W<<<192, 256, 0, stream>>>(W, Wr);
    gemm_gate_mfma<<<4096, 256, 0, stream>>>(x, Wr, (unsigned*)d_out);
    scan_pass1<<<BB * CC / 2, 256, 0, stream>>>((const unsigned*)d_out, P_arr, U_arr);
    scan_pass2<<<BB, 256, 0, stream>>>(h_prev, P_arr, U_arr, Hin);
    scan_pass3<<<BB * CC / 2, 256, 0, stream>>>(Hin, (unsigned*)d_out);
}